// Round 1
// baseline (2003.138 us; speedup 1.0000x reference)
//
#include <hip/hip_runtime.h>
#include <math.h>

// GPT-2 block forward, fp32 baseline.
// B=2, T=2048, C=1024, H=16, Dh=64. M = B*T = 4096.
constexpr int TDIM = 2048;
constexpr int BDIM = 2;
constexpr int CDIM = 1024;
constexpr int HEADS = 16;
constexpr int DH = 64;
constexpr int MDIM = BDIM * TDIM; // 4096

__device__ __forceinline__ float gelu_f(float x) {
    const float c0 = 0.7978845608028654f; // sqrt(2/pi)
    float x3 = x * x * x;
    float t = tanhf(c0 * (x + 0.044715f * x3));
    return 0.5f * x * (1.0f + t);
}

// ---------------- LayerNorm: one block (256 thr) per row of 1024 ----------------
__global__ __launch_bounds__(256) void ln_kernel(
    const float* __restrict__ x, const float* __restrict__ w,
    const float* __restrict__ b, float* __restrict__ out) {
    int row = blockIdx.x;
    int tid = threadIdx.x;
    const float* xr = x + (size_t)row * CDIM;
    float4 v = *(const float4*)(xr + tid * 4);
    float s  = v.x + v.y + v.z + v.w;
    float ss = v.x * v.x + v.y * v.y + v.z * v.z + v.w * v.w;
#pragma unroll
    for (int off = 32; off >= 1; off >>= 1) {
        s  += __shfl_xor(s, off);
        ss += __shfl_xor(ss, off);
    }
    __shared__ float rs[4], rss[4];
    int wave = tid >> 6;
    if ((tid & 63) == 0) { rs[wave] = s; rss[wave] = ss; }
    __syncthreads();
    s  = rs[0] + rs[1] + rs[2] + rs[3];
    ss = rss[0] + rss[1] + rss[2] + rss[3];
    float mean = s * (1.0f / CDIM);
    float var  = ss * (1.0f / CDIM) - mean * mean;
    float rstd = rsqrtf(var + 1e-5f);
    float4 wv = *(const float4*)(w + tid * 4);
    float4 bv = *(const float4*)(b + tid * 4);
    float4 o;
    o.x = (v.x - mean) * rstd * wv.x + bv.x;
    o.y = (v.y - mean) * rstd * wv.y + bv.y;
    o.z = (v.z - mean) * rstd * wv.z + bv.z;
    o.w = (v.w - mean) * rstd * wv.w + bv.w;
    *(float4*)(out + (size_t)row * CDIM + tid * 4) = o;
}

// ---------------- fp32 GEMM: C = A[M,K] @ W[K,N] (+bias, +res, +gelu) ----------------
// 128x128 tile, BK=8, 256 threads, 8x8 micro-tile per thread.
enum { EP_BIAS = 0, EP_BIAS_RES = 1, EP_BIAS_GELU = 2 };

template <int MODE>
__global__ __launch_bounds__(256) void gemm_f32(
    const float* __restrict__ A, const float* __restrict__ W,
    const float* __restrict__ bias, const float* __restrict__ res,
    float* __restrict__ Cout, int M, int N, int K) {
    __shared__ float As[8][128]; // stored transposed: As[k][m]
    __shared__ float Bs[8][128];
    int tid = threadIdx.x;
    int row0 = blockIdx.y * 128, col0 = blockIdx.x * 128;
    int ty = tid >> 4, tx = tid & 15;
    float acc[8][8] = {};
    int arow = tid >> 1, acol4 = (tid & 1) * 4;
    int brow = tid >> 5, bcol4 = (tid & 31) * 4;
    const float* Aptr = A + (size_t)(row0 + arow) * K + acol4;
    const float* Wptr = W + (size_t)brow * N + col0 + bcol4;

    for (int k0 = 0; k0 < K; k0 += 8) {
        float4 a4 = *(const float4*)(Aptr + k0);
        float4 b4 = *(const float4*)(Wptr + (size_t)k0 * N);
        __syncthreads();
        As[acol4 + 0][arow] = a4.x;
        As[acol4 + 1][arow] = a4.y;
        As[acol4 + 2][arow] = a4.z;
        As[acol4 + 3][arow] = a4.w;
        *(float4*)&Bs[brow][bcol4] = b4;
        __syncthreads();
#pragma unroll
        for (int kk = 0; kk < 8; ++kk) {
            float a[8], b[8];
            *(float4*)(a)     = *(const float4*)&As[kk][ty * 8];
            *(float4*)(a + 4) = *(const float4*)&As[kk][ty * 8 + 4];
            *(float4*)(b)     = *(const float4*)&Bs[kk][tx * 8];
            *(float4*)(b + 4) = *(const float4*)&Bs[kk][tx * 8 + 4];
#pragma unroll
            for (int i = 0; i < 8; ++i)
#pragma unroll
                for (int j = 0; j < 8; ++j)
                    acc[i][j] = fmaf(a[i], b[j], acc[i][j]);
        }
    }
#pragma unroll
    for (int i = 0; i < 8; ++i) {
        int r = row0 + ty * 8 + i;
#pragma unroll
        for (int j = 0; j < 8; j += 4) {
            int c = col0 + tx * 8 + j;
            float4 bv = *(const float4*)(bias + c);
            float4 o;
            o.x = acc[i][j + 0] + bv.x;
            o.y = acc[i][j + 1] + bv.y;
            o.z = acc[i][j + 2] + bv.z;
            o.w = acc[i][j + 3] + bv.w;
            if (MODE == EP_BIAS_GELU) {
                o.x = gelu_f(o.x); o.y = gelu_f(o.y);
                o.z = gelu_f(o.z); o.w = gelu_f(o.w);
            }
            if (MODE == EP_BIAS_RES) {
                float4 rv = *(const float4*)(res + (size_t)r * N + c);
                o.x += rv.x; o.y += rv.y; o.z += rv.z; o.w += rv.w;
            }
            *(float4*)(Cout + (size_t)r * N + c) = o;
        }
    }
}

// ---------------- Flash attention fp32: 64-row Q tile per block ----------------
// grid = (B*H, T/64), block = 256. qkv layout [B*T, 3C], head h cols h*64 in each third.
__global__ __launch_bounds__(256) void attn_kernel(
    const float* __restrict__ qkv, float* __restrict__ y) {
    int bh = blockIdx.x;
    int b = bh >> 4, h = bh & 15;
    int qy = blockIdx.y;
    int q0 = qy * 64;
    int tid = threadIdx.x;
    int ty4 = (tid >> 4) * 4, tx4 = (tid & 15) * 4;
    const size_t base = (size_t)b * TDIM * (3 * CDIM);
    const float* qb = qkv + base + h * DH;
    const float* kb = qkv + base + CDIM + h * DH;
    const float* vb = qkv + base + 2 * CDIM + h * DH;

    __shared__ float Qs[64][65];
    __shared__ float Ks[64][65];
    __shared__ float Vs[64][65];
    __shared__ float Ps[64][65];

    // load Q tile
    for (int i = tid; i < 1024; i += 256) {
        int r = i >> 4, seg = (i & 15) * 4;
        float4 t4 = *(const float4*)(qb + (size_t)(q0 + r) * (3 * CDIM) + seg);
        Qs[r][seg] = t4.x; Qs[r][seg + 1] = t4.y;
        Qs[r][seg + 2] = t4.z; Qs[r][seg + 3] = t4.w;
    }

    float m[4], l[4], o[4][4];
#pragma unroll
    for (int i = 0; i < 4; ++i) {
        m[i] = -1e30f; l[i] = 0.f;
#pragma unroll
        for (int j = 0; j < 4; ++j) o[i][j] = 0.f;
    }

    for (int kt = 0; kt <= qy; ++kt) {
        __syncthreads(); // Q visible; prev PV done before K/V overwrite
        for (int i = tid; i < 1024; i += 256) {
            int r = i >> 4, seg = (i & 15) * 4;
            float4 k4 = *(const float4*)(kb + (size_t)(kt * 64 + r) * (3 * CDIM) + seg);
            Ks[r][seg] = k4.x; Ks[r][seg + 1] = k4.y;
            Ks[r][seg + 2] = k4.z; Ks[r][seg + 3] = k4.w;
            float4 v4 = *(const float4*)(vb + (size_t)(kt * 64 + r) * (3 * CDIM) + seg);
            Vs[r][seg] = v4.x; Vs[r][seg + 1] = v4.y;
            Vs[r][seg + 2] = v4.z; Vs[r][seg + 3] = v4.w;
        }
        __syncthreads();

        // S = Q K^T (4x4 per thread)
        float s_[4][4] = {};
#pragma unroll 4
        for (int d = 0; d < 64; ++d) {
            float a0 = Qs[ty4 + 0][d], a1 = Qs[ty4 + 1][d];
            float a2 = Qs[ty4 + 2][d], a3 = Qs[ty4 + 3][d];
            float c0 = Ks[tx4 + 0][d], c1 = Ks[tx4 + 1][d];
            float c2 = Ks[tx4 + 2][d], c3 = Ks[tx4 + 3][d];
            s_[0][0] = fmaf(a0, c0, s_[0][0]); s_[0][1] = fmaf(a0, c1, s_[0][1]);
            s_[0][2] = fmaf(a0, c2, s_[0][2]); s_[0][3] = fmaf(a0, c3, s_[0][3]);
            s_[1][0] = fmaf(a1, c0, s_[1][0]); s_[1][1] = fmaf(a1, c1, s_[1][1]);
            s_[1][2] = fmaf(a1, c2, s_[1][2]); s_[1][3] = fmaf(a1, c3, s_[1][3]);
            s_[2][0] = fmaf(a2, c0, s_[2][0]); s_[2][1] = fmaf(a2, c1, s_[2][1]);
            s_[2][2] = fmaf(a2, c2, s_[2][2]); s_[2][3] = fmaf(a2, c3, s_[2][3]);
            s_[3][0] = fmaf(a3, c0, s_[3][0]); s_[3][1] = fmaf(a3, c1, s_[3][1]);
            s_[3][2] = fmaf(a3, c2, s_[3][2]); s_[3][3] = fmaf(a3, c3, s_[3][3]);
        }

        // scale + causal mask (only the diagonal tile needs masking)
        bool diag = (kt == qy);
#pragma unroll
        for (int i = 0; i < 4; ++i)
#pragma unroll
            for (int j = 0; j < 4; ++j) {
                float v = s_[i][j] * 0.125f; // 1/sqrt(64)
                if (diag && (tx4 + j) > (ty4 + i)) v = -1e30f;
                s_[i][j] = v;
            }

        // online softmax: row reduce across the 16 lanes of each row group
        float mnew[4], sf_[4];
#pragma unroll
        for (int i = 0; i < 4; ++i) {
            float pm = fmaxf(fmaxf(s_[i][0], s_[i][1]), fmaxf(s_[i][2], s_[i][3]));
#pragma unroll
            for (int off = 1; off < 16; off <<= 1) pm = fmaxf(pm, __shfl_xor(pm, off));
            mnew[i] = fmaxf(m[i], pm);
            sf_[i] = expf(m[i] - mnew[i]);
        }
#pragma unroll
        for (int i = 0; i < 4; ++i) {
            float r = 0.f;
#pragma unroll
            for (int j = 0; j < 4; ++j) {
                float p = expf(s_[i][j] - mnew[i]);
                s_[i][j] = p;
                r += p;
            }
#pragma unroll
            for (int off = 1; off < 16; off <<= 1) r += __shfl_xor(r, off);
            l[i] = l[i] * sf_[i] + r;
            m[i] = mnew[i];
        }
#pragma unroll
        for (int i = 0; i < 4; ++i)
#pragma unroll
            for (int j = 0; j < 4; ++j) {
                o[i][j] *= sf_[i];
                Ps[ty4 + i][tx4 + j] = s_[i][j];
            }
        __syncthreads();

        // O += P @ V
#pragma unroll 4
        for (int k = 0; k < 64; ++k) {
            float p0 = Ps[ty4 + 0][k], p1 = Ps[ty4 + 1][k];
            float p2 = Ps[ty4 + 2][k], p3 = Ps[ty4 + 3][k];
            float v0 = Vs[k][tx4 + 0], v1 = Vs[k][tx4 + 1];
            float v2 = Vs[k][tx4 + 2], v3 = Vs[k][tx4 + 3];
            o[0][0] = fmaf(p0, v0, o[0][0]); o[0][1] = fmaf(p0, v1, o[0][1]);
            o[0][2] = fmaf(p0, v2, o[0][2]); o[0][3] = fmaf(p0, v3, o[0][3]);
            o[1][0] = fmaf(p1, v0, o[1][0]); o[1][1] = fmaf(p1, v1, o[1][1]);
            o[1][2] = fmaf(p1, v2, o[1][2]); o[1][3] = fmaf(p1, v3, o[1][3]);
            o[2][0] = fmaf(p2, v0, o[2][0]); o[2][1] = fmaf(p2, v1, o[2][1]);
            o[2][2] = fmaf(p2, v2, o[2][2]); o[2][3] = fmaf(p2, v3, o[2][3]);
            o[3][0] = fmaf(p3, v0, o[3][0]); o[3][1] = fmaf(p3, v1, o[3][1]);
            o[3][2] = fmaf(p3, v2, o[3][2]); o[3][3] = fmaf(p3, v3, o[3][3]);
        }
    }

    // write y[b, q0+r, h*64 + d]
#pragma unroll
    for (int i = 0; i < 4; ++i) {
        float il = 1.0f / l[i];
        float4 ov = make_float4(o[i][0] * il, o[i][1] * il, o[i][2] * il, o[i][3] * il);
        *(float4*)(y + (size_t)(b * TDIM + q0 + ty4 + i) * CDIM + h * DH + tx4) = ov;
    }
}

// ---------------- launch ----------------
extern "C" void kernel_launch(void* const* d_in, const int* in_sizes, int n_in,
                              void* d_out, int out_size, void* d_ws, size_t ws_size,
                              hipStream_t stream) {
    const float* x      = (const float*)d_in[0];
    const float* ln1_w  = (const float*)d_in[1];
    const float* ln1_b  = (const float*)d_in[2];
    const float* W_attn = (const float*)d_in[3];
    const float* b_attn = (const float*)d_in[4];
    const float* W_o    = (const float*)d_in[5];
    const float* b_o    = (const float*)d_in[6];
    const float* ln2_w  = (const float*)d_in[7];
    const float* ln2_b  = (const float*)d_in[8];
    const float* W_fc   = (const float*)d_in[9];
    const float* b_fc   = (const float*)d_in[10];
    const float* W_proj = (const float*)d_in[11];
    const float* b_proj = (const float*)d_in[12];
    float* out = (float*)d_out;

    char* ws = (char*)d_ws;
    // h: 16 MB (LN1 out -> attn y -> LN2 out), big: 64 MB (qkv 48 MB -> fc 64 MB)
    float* h   = (float*)(ws);
    float* big = (float*)(ws + (size_t)16 * 1024 * 1024);
    float* x1  = out; // residual stream lives in d_out (per-element safe aliasing)

    // 1. h = LN1(x)
    hipLaunchKernelGGL(ln_kernel, dim3(MDIM), dim3(256), 0, stream, x, ln1_w, ln1_b, h);
    // 2. qkv = h @ W_attn + b_attn   [4096, 3072]
    hipLaunchKernelGGL((gemm_f32<EP_BIAS>), dim3(3 * CDIM / 128, MDIM / 128), dim3(256), 0,
                       stream, h, W_attn, b_attn, nullptr, big, MDIM, 3 * CDIM, CDIM);
    // 3. y = attention(qkv)  -> h (reuse)
    hipLaunchKernelGGL(attn_kernel, dim3(BDIM * HEADS, TDIM / 64), dim3(256), 0, stream,
                       big, h);
    // 4. x1 = x + y @ W_o + b_o
    hipLaunchKernelGGL((gemm_f32<EP_BIAS_RES>), dim3(CDIM / 128, MDIM / 128), dim3(256), 0,
                       stream, h, W_o, b_o, x, x1, MDIM, CDIM, CDIM);
    // 5. h = LN2(x1)
    hipLaunchKernelGGL(ln_kernel, dim3(MDIM), dim3(256), 0, stream, x1, ln2_w, ln2_b, h);
    // 6. fc = gelu(h @ W_fc + b_fc)   [4096, 4096]
    hipLaunchKernelGGL((gemm_f32<EP_BIAS_GELU>), dim3(4 * CDIM / 128, MDIM / 128), dim3(256),
                       0, stream, h, W_fc, b_fc, nullptr, big, MDIM, 4 * CDIM, CDIM);
    // 7. out = x1 + fc @ W_proj + b_proj
    hipLaunchKernelGGL((gemm_f32<EP_BIAS_RES>), dim3(CDIM / 128, MDIM / 128), dim3(256), 0,
                       stream, big, W_proj, b_proj, x1, out, MDIM, CDIM, 4 * CDIM);
}

// Round 2
// 750.826 us; speedup vs baseline: 2.6679x; 2.6679x over previous
//
#include <hip/hip_runtime.h>
#include <math.h>

// GPT-2 block forward. bf16 MFMA GEMMs + fp32 flash attention.
// B=2, T=2048, C=1024, H=16, Dh=64. M = B*T = 4096.
constexpr int TDIM = 2048;
constexpr int BDIM = 2;
constexpr int CDIM = 1024;
constexpr int HEADS = 16;
constexpr int DH = 64;
constexpr int MDIM = BDIM * TDIM; // 4096

typedef short bf16x8 __attribute__((ext_vector_type(8)));
typedef float f32x4 __attribute__((ext_vector_type(4)));

__device__ __forceinline__ float b2f(unsigned short u) {
    union { float f; unsigned int i; } v; v.i = ((unsigned int)u) << 16; return v.f;
}
__device__ __forceinline__ unsigned short f2b(float f) {
    union { float f; unsigned int i; } v; v.f = f;
    unsigned int r = (v.i + 0x7FFFu + ((v.i >> 16) & 1u)) >> 16;
    return (unsigned short)r;
}
__device__ __forceinline__ float gelu_f(float x) {
    const float c0 = 0.7978845608028654f; // sqrt(2/pi)
    float x3 = x * x * x;
    float t = tanhf(c0 * (x + 0.044715f * x3));
    return 0.5f * x * (1.0f + t);
}
__device__ __forceinline__ void async_copy16(const void* g, void* l) {
    __builtin_amdgcn_global_load_lds(
        (const __attribute__((address_space(1))) unsigned int*)g,
        (__attribute__((address_space(3))) unsigned int*)l, 16, 0, 0);
}

// ---------------- weight transpose + cast: W[K][N] f32 -> Wt[N][K] bf16 ----------------
__global__ __launch_bounds__(256) void transpose_cast(
    const float* __restrict__ W, unsigned short* __restrict__ Wt, int K, int N) {
    __shared__ float tile[32][33];
    int n0 = blockIdx.x * 32, k0 = blockIdx.y * 32;
    int tx = threadIdx.x & 31, ty = threadIdx.x >> 5; // 32 x 8
#pragma unroll
    for (int i = 0; i < 32; i += 8)
        tile[ty + i][tx] = W[(size_t)(k0 + ty + i) * N + n0 + tx];
    __syncthreads();
#pragma unroll
    for (int i = 0; i < 32; i += 8)
        Wt[(size_t)(n0 + ty + i) * K + k0 + tx] = f2b(tile[tx][ty + i]);
}

// ---------------- LayerNorm: f32 in -> bf16 out, one block per row of 1024 ----------------
__global__ __launch_bounds__(256) void ln_kernel(
    const float* __restrict__ x, const float* __restrict__ w,
    const float* __restrict__ b, unsigned short* __restrict__ out) {
    int row = blockIdx.x;
    int tid = threadIdx.x;
    const float* xr = x + (size_t)row * CDIM;
    float4 v = *(const float4*)(xr + tid * 4);
    float s  = v.x + v.y + v.z + v.w;
    float ss = v.x * v.x + v.y * v.y + v.z * v.z + v.w * v.w;
#pragma unroll
    for (int off = 32; off >= 1; off >>= 1) {
        s  += __shfl_xor(s, off);
        ss += __shfl_xor(ss, off);
    }
    __shared__ float rs[4], rss[4];
    int wave = tid >> 6;
    if ((tid & 63) == 0) { rs[wave] = s; rss[wave] = ss; }
    __syncthreads();
    s  = rs[0] + rs[1] + rs[2] + rs[3];
    ss = rss[0] + rss[1] + rss[2] + rss[3];
    float mean = s * (1.0f / CDIM);
    float var  = ss * (1.0f / CDIM) - mean * mean;
    float rstd = rsqrtf(var + 1e-5f);
    float4 wv = *(const float4*)(w + tid * 4);
    float4 bv = *(const float4*)(b + tid * 4);
    ushort4 o;
    o.x = f2b((v.x - mean) * rstd * wv.x + bv.x);
    o.y = f2b((v.y - mean) * rstd * wv.y + bv.y);
    o.z = f2b((v.z - mean) * rstd * wv.z + bv.z);
    o.w = f2b((v.w - mean) * rstd * wv.w + bv.w);
    *(ushort4*)(out + (size_t)row * CDIM + tid * 4) = o;
}

// ---------------- bf16 MFMA GEMM: C = A[M,K] @ Wt[N,K]^T (+bias, +res, +gelu) ----------
// 128x128 tile, BK=64, 256 threads (4 waves, 2x2), 64x64 per wave, 4x4 frags of 16x16.
// LDS tiles XOR-swizzled (slot ^= row&7) so staging writes linear and frag reads are
// 2-way-bank (free). Staging via global_load_lds dwordx4 with pre-swizzled global source.
// MODE: 0 = bias -> bf16 out; 1 = bias + res -> f32 out; 2 = bias + gelu -> bf16 out.
template <int MODE>
__global__ __launch_bounds__(256) void gemm_bf16(
    const unsigned short* __restrict__ A, const unsigned short* __restrict__ Wt,
    const float* __restrict__ bias, const float* __restrict__ res,
    void* __restrict__ Cout, int M, int N, int K) {
    __shared__ __align__(16) short As[128 * 64];
    __shared__ __align__(16) short Bs[128 * 64];
    const int tid = threadIdx.x;
    const int lane = tid & 63, w = tid >> 6;
    const int wr = w >> 1, wc = w & 1;
    const int row0 = blockIdx.y * 128, col0 = blockIdx.x * 128;

    // --- staging geometry: each wave-instruction stages 8 rows x 128 B ---
    const int sr = lane >> 3;                   // 0..7: row within 8-row group
    const int sc = 8 * ((lane & 7) ^ sr);       // element col, pre-swizzled source
    const unsigned short* gA = A  + (size_t)(row0 + w * 8 + sr) * K + sc;
    const unsigned short* gB = Wt + (size_t)(col0 + w * 8 + sr) * K + sc;
    short* ldsA = As + (w * 8) * 64;            // wave-uniform dst base
    short* ldsB = Bs + (w * 8) * 64;

    f32x4 acc[4][4] = {};
    const int h = lane >> 4;                    // 0..3
    const int r15 = lane & 15;

    for (int k0 = 0; k0 < K; k0 += 64) {
        __syncthreads();
#pragma unroll
        for (int i = 0; i < 4; ++i) {
            async_copy16(gA + (size_t)i * 32 * K + k0, ldsA + i * 32 * 64);
            async_copy16(gB + (size_t)i * 32 * K + k0, ldsB + i * 32 * 64);
        }
        __syncthreads();
#pragma unroll
        for (int ks = 0; ks < 2; ++ks) {
            bf16x8 af[4], bfr[4];
#pragma unroll
            for (int i = 0; i < 4; ++i) {
                int ra = wr * 64 + i * 16 + r15;
                int offa = ra * 128 + ((ks * 64 + h * 16) ^ ((ra & 7) << 4));
                af[i] = *(const bf16x8*)((const char*)As + offa);
                int rb = wc * 64 + i * 16 + r15;
                int offb = rb * 128 + ((ks * 64 + h * 16) ^ ((rb & 7) << 4));
                bfr[i] = *(const bf16x8*)((const char*)Bs + offb);
            }
#pragma unroll
            for (int i = 0; i < 4; ++i)
#pragma unroll
                for (int j = 0; j < 4; ++j)
                    acc[i][j] = __builtin_amdgcn_mfma_f32_16x16x32_bf16(
                        af[i], bfr[j], acc[i][j], 0, 0, 0);
        }
    }

    // --- epilogue: C[row = (lane>>4)*4 + q][col = lane&15] per 16x16 frag ---
#pragma unroll
    for (int i = 0; i < 4; ++i) {
#pragma unroll
        for (int j = 0; j < 4; ++j) {
            int c = col0 + wc * 64 + j * 16 + r15;
            float bv = bias[c];
#pragma unroll
            for (int q = 0; q < 4; ++q) {
                int rr = row0 + wr * 64 + i * 16 + h * 4 + q;
                float v = acc[i][j][q] + bv;
                if (MODE == 2) v = gelu_f(v);
                if (MODE == 1) v += res[(size_t)rr * N + c];
                if (MODE == 1) ((float*)Cout)[(size_t)rr * N + c] = v;
                else ((unsigned short*)Cout)[(size_t)rr * N + c] = f2b(v);
            }
        }
    }
}

// ---------------- Flash attention fp32 (bf16 qkv in, bf16 y out) ----------------
// grid = (B*H, T/64), block = 256. qkv layout [B*T, 3C] bf16.
__global__ __launch_bounds__(256) void attn_kernel(
    const unsigned short* __restrict__ qkv, unsigned short* __restrict__ y) {
    int bh = blockIdx.x;
    int b = bh >> 4, hh = bh & 15;
    int qy = blockIdx.y;
    int q0 = qy * 64;
    int tid = threadIdx.x;
    int ty4 = (tid >> 4) * 4, tx4 = (tid & 15) * 4;
    const size_t base = (size_t)b * TDIM * (3 * CDIM);
    const unsigned short* qb = qkv + base + hh * DH;
    const unsigned short* kb = qkv + base + CDIM + hh * DH;
    const unsigned short* vb = qkv + base + 2 * CDIM + hh * DH;

    __shared__ float Qs[64][65];
    __shared__ float Ks[64][65];
    __shared__ float Vs[64][65];
    __shared__ float Ps[64][65];

    for (int i = tid; i < 1024; i += 256) {
        int r = i >> 4, seg = (i & 15) * 4;
        ushort4 t4 = *(const ushort4*)(qb + (size_t)(q0 + r) * (3 * CDIM) + seg);
        Qs[r][seg] = b2f(t4.x); Qs[r][seg + 1] = b2f(t4.y);
        Qs[r][seg + 2] = b2f(t4.z); Qs[r][seg + 3] = b2f(t4.w);
    }

    float m[4], l[4], o[4][4];
#pragma unroll
    for (int i = 0; i < 4; ++i) {
        m[i] = -1e30f; l[i] = 0.f;
#pragma unroll
        for (int j = 0; j < 4; ++j) o[i][j] = 0.f;
    }

    for (int kt = 0; kt <= qy; ++kt) {
        __syncthreads();
        for (int i = tid; i < 1024; i += 256) {
            int r = i >> 4, seg = (i & 15) * 4;
            ushort4 k4 = *(const ushort4*)(kb + (size_t)(kt * 64 + r) * (3 * CDIM) + seg);
            Ks[r][seg] = b2f(k4.x); Ks[r][seg + 1] = b2f(k4.y);
            Ks[r][seg + 2] = b2f(k4.z); Ks[r][seg + 3] = b2f(k4.w);
            ushort4 v4 = *(const ushort4*)(vb + (size_t)(kt * 64 + r) * (3 * CDIM) + seg);
            Vs[r][seg] = b2f(v4.x); Vs[r][seg + 1] = b2f(v4.y);
            Vs[r][seg + 2] = b2f(v4.z); Vs[r][seg + 3] = b2f(v4.w);
        }
        __syncthreads();

        float s_[4][4] = {};
#pragma unroll 4
        for (int d = 0; d < 64; ++d) {
            float a0 = Qs[ty4 + 0][d], a1 = Qs[ty4 + 1][d];
            float a2 = Qs[ty4 + 2][d], a3 = Qs[ty4 + 3][d];
            float c0 = Ks[tx4 + 0][d], c1 = Ks[tx4 + 1][d];
            float c2 = Ks[tx4 + 2][d], c3 = Ks[tx4 + 3][d];
            s_[0][0] = fmaf(a0, c0, s_[0][0]); s_[0][1] = fmaf(a0, c1, s_[0][1]);
            s_[0][2] = fmaf(a0, c2, s_[0][2]); s_[0][3] = fmaf(a0, c3, s_[0][3]);
            s_[1][0] = fmaf(a1, c0, s_[1][0]); s_[1][1] = fmaf(a1, c1, s_[1][1]);
            s_[1][2] = fmaf(a1, c2, s_[1][2]); s_[1][3] = fmaf(a1, c3, s_[1][3]);
            s_[2][0] = fmaf(a2, c0, s_[2][0]); s_[2][1] = fmaf(a2, c1, s_[2][1]);
            s_[2][2] = fmaf(a2, c2, s_[2][2]); s_[2][3] = fmaf(a2, c3, s_[2][3]);
            s_[3][0] = fmaf(a3, c0, s_[3][0]); s_[3][1] = fmaf(a3, c1, s_[3][1]);
            s_[3][2] = fmaf(a3, c2, s_[3][2]); s_[3][3] = fmaf(a3, c3, s_[3][3]);
        }

        bool diag = (kt == qy);
#pragma unroll
        for (int i = 0; i < 4; ++i)
#pragma unroll
            for (int j = 0; j < 4; ++j) {
                float v = s_[i][j] * 0.125f;
                if (diag && (tx4 + j) > (ty4 + i)) v = -1e30f;
                s_[i][j] = v;
            }

        float mnew[4], sf_[4];
#pragma unroll
        for (int i = 0; i < 4; ++i) {
            float pm = fmaxf(fmaxf(s_[i][0], s_[i][1]), fmaxf(s_[i][2], s_[i][3]));
#pragma unroll
            for (int off = 1; off < 16; off <<= 1) pm = fmaxf(pm, __shfl_xor(pm, off));
            mnew[i] = fmaxf(m[i], pm);
            sf_[i] = expf(m[i] - mnew[i]);
        }
#pragma unroll
        for (int i = 0; i < 4; ++i) {
            float r = 0.f;
#pragma unroll
            for (int j = 0; j < 4; ++j) {
                float p = expf(s_[i][j] - mnew[i]);
                s_[i][j] = p;
                r += p;
            }
#pragma unroll
            for (int off = 1; off < 16; off <<= 1) r += __shfl_xor(r, off);
            l[i] = l[i] * sf_[i] + r;
            m[i] = mnew[i];
        }
#pragma unroll
        for (int i = 0; i < 4; ++i)
#pragma unroll
            for (int j = 0; j < 4; ++j) {
                o[i][j] *= sf_[i];
                Ps[ty4 + i][tx4 + j] = s_[i][j];
            }
        __syncthreads();

#pragma unroll 4
        for (int k = 0; k < 64; ++k) {
            float p0 = Ps[ty4 + 0][k], p1 = Ps[ty4 + 1][k];
            float p2 = Ps[ty4 + 2][k], p3 = Ps[ty4 + 3][k];
            float v0 = Vs[k][tx4 + 0], v1 = Vs[k][tx4 + 1];
            float v2 = Vs[k][tx4 + 2], v3 = Vs[k][tx4 + 3];
            o[0][0] = fmaf(p0, v0, o[0][0]); o[0][1] = fmaf(p0, v1, o[0][1]);
            o[0][2] = fmaf(p0, v2, o[0][2]); o[0][3] = fmaf(p0, v3, o[0][3]);
            o[1][0] = fmaf(p1, v0, o[1][0]); o[1][1] = fmaf(p1, v1, o[1][1]);
            o[1][2] = fmaf(p1, v2, o[1][2]); o[1][3] = fmaf(p1, v3, o[1][3]);
            o[2][0] = fmaf(p2, v0, o[2][0]); o[2][1] = fmaf(p2, v1, o[2][1]);
            o[2][2] = fmaf(p2, v2, o[2][2]); o[2][3] = fmaf(p2, v3, o[2][3]);
            o[3][0] = fmaf(p3, v0, o[3][0]); o[3][1] = fmaf(p3, v1, o[3][1]);
            o[3][2] = fmaf(p3, v2, o[3][2]); o[3][3] = fmaf(p3, v3, o[3][3]);
        }
    }

#pragma unroll
    for (int i = 0; i < 4; ++i) {
        float il = 1.0f / l[i];
        ushort4 ov;
        ov.x = f2b(o[i][0] * il); ov.y = f2b(o[i][1] * il);
        ov.z = f2b(o[i][2] * il); ov.w = f2b(o[i][3] * il);
        *(ushort4*)(y + (size_t)(b * TDIM + q0 + ty4 + i) * CDIM + hh * DH + tx4) = ov;
    }
}

// ---------------- launch ----------------
extern "C" void kernel_launch(void* const* d_in, const int* in_sizes, int n_in,
                              void* d_out, int out_size, void* d_ws, size_t ws_size,
                              hipStream_t stream) {
    const float* x      = (const float*)d_in[0];
    const float* ln1_w  = (const float*)d_in[1];
    const float* ln1_b  = (const float*)d_in[2];
    const float* W_attn = (const float*)d_in[3];
    const float* b_attn = (const float*)d_in[4];
    const float* W_o    = (const float*)d_in[5];
    const float* b_o    = (const float*)d_in[6];
    const float* ln2_w  = (const float*)d_in[7];
    const float* ln2_b  = (const float*)d_in[8];
    const float* W_fc   = (const float*)d_in[9];
    const float* b_fc   = (const float*)d_in[10];
    const float* W_proj = (const float*)d_in[11];
    const float* b_proj = (const float*)d_in[12];
    float* out = (float*)d_out;

    char* ws = (char*)d_ws;
    const size_t MB = 1024 * 1024;
    unsigned short* h_bf    = (unsigned short*)(ws);             // 8 MB  [4096,1024]
    unsigned short* big     = (unsigned short*)(ws + 8 * MB);    // 32 MB qkv[4096,3072] / fcact[4096,4096]
    unsigned short* Wt_attn = (unsigned short*)(ws + 40 * MB);   // 6 MB  [3072,1024]
    unsigned short* Wt_o    = (unsigned short*)(ws + 46 * MB);   // 2 MB  [1024,1024]
    unsigned short* Wt_fc   = (unsigned short*)(ws + 48 * MB);   // 8 MB  [4096,1024]
    unsigned short* Wt_proj = (unsigned short*)(ws + 56 * MB);   // 8 MB  [1024,4096]
    float* x1 = out;

    // 0. weight transpose + cast (W[K][N] -> Wt[N][K] bf16)
    hipLaunchKernelGGL(transpose_cast, dim3(96, 32),  dim3(256), 0, stream, W_attn, Wt_attn, CDIM, 3 * CDIM);
    hipLaunchKernelGGL(transpose_cast, dim3(32, 32),  dim3(256), 0, stream, W_o,    Wt_o,    CDIM, CDIM);
    hipLaunchKernelGGL(transpose_cast, dim3(128, 32), dim3(256), 0, stream, W_fc,   Wt_fc,   CDIM, 4 * CDIM);
    hipLaunchKernelGGL(transpose_cast, dim3(32, 128), dim3(256), 0, stream, W_proj, Wt_proj, 4 * CDIM, CDIM);

    // 1. h = LN1(x)  (bf16)
    hipLaunchKernelGGL(ln_kernel, dim3(MDIM), dim3(256), 0, stream, x, ln1_w, ln1_b, h_bf);
    // 2. qkv = h @ W_attn + b_attn  -> bf16 [4096, 3072]
    hipLaunchKernelGGL((gemm_bf16<0>), dim3(3 * CDIM / 128, MDIM / 128), dim3(256), 0,
                       stream, h_bf, Wt_attn, b_attn, nullptr, big, MDIM, 3 * CDIM, CDIM);
    // 3. y = attention(qkv) -> h_bf (bf16)
    hipLaunchKernelGGL(attn_kernel, dim3(BDIM * HEADS, TDIM / 64), dim3(256), 0, stream,
                       big, h_bf);
    // 4. x1 = x + y @ W_o + b_o  (f32)
    hipLaunchKernelGGL((gemm_bf16<1>), dim3(CDIM / 128, MDIM / 128), dim3(256), 0,
                       stream, h_bf, Wt_o, b_o, x, x1, MDIM, CDIM, CDIM);
    // 5. h = LN2(x1) (bf16)
    hipLaunchKernelGGL(ln_kernel, dim3(MDIM), dim3(256), 0, stream, x1, ln2_w, ln2_b, h_bf);
    // 6. fcact = gelu(h @ W_fc + b_fc) -> bf16 [4096, 4096]
    hipLaunchKernelGGL((gemm_bf16<2>), dim3(4 * CDIM / 128, MDIM / 128), dim3(256), 0,
                       stream, h_bf, Wt_fc, b_fc, nullptr, big, MDIM, 4 * CDIM, CDIM);
    // 7. out = x1 + fcact @ W_proj + b_proj (f32)
    hipLaunchKernelGGL((gemm_bf16<1>), dim3(CDIM / 128, MDIM / 128), dim3(256), 0,
                       stream, big, Wt_proj, b_proj, x1, out, MDIM, CDIM, 4 * CDIM);
}

// Round 3
// 406.343 us; speedup vs baseline: 4.9297x; 1.8478x over previous
//
#include <hip/hip_runtime.h>
#include <math.h>

// GPT-2 block forward. bf16 MFMA GEMMs + bf16 MFMA flash attention.
// B=2, T=2048, C=1024, H=16, Dh=64. M = B*T = 4096.
constexpr int TDIM = 2048;
constexpr int BDIM = 2;
constexpr int CDIM = 1024;
constexpr int HEADS = 16;
constexpr int DH = 64;
constexpr int MDIM = BDIM * TDIM; // 4096

typedef short bf16x8 __attribute__((ext_vector_type(8)));
typedef float f32x4 __attribute__((ext_vector_type(4)));

__device__ __forceinline__ float b2f(unsigned short u) {
    union { float f; unsigned int i; } v; v.i = ((unsigned int)u) << 16; return v.f;
}
__device__ __forceinline__ unsigned short f2b(float f) {
    union { float f; unsigned int i; } v; v.f = f;
    unsigned int r = (v.i + 0x7FFFu + ((v.i >> 16) & 1u)) >> 16;
    return (unsigned short)r;
}
__device__ __forceinline__ float gelu_f(float x) {
    const float c0 = 0.7978845608028654f; // sqrt(2/pi)
    float x3 = x * x * x;
    float t = tanhf(c0 * (x + 0.044715f * x3));
    return 0.5f * x * (1.0f + t);
}
__device__ __forceinline__ void async_copy16(const void* g, void* l) {
    __builtin_amdgcn_global_load_lds(
        (const __attribute__((address_space(1))) unsigned int*)g,
        (__attribute__((address_space(3))) unsigned int*)l, 16, 0, 0);
}

// ---------------- weight transpose + cast: W[K][N] f32 -> Wt[N][K] bf16 ----------------
__global__ __launch_bounds__(256) void transpose_cast(
    const float* __restrict__ W, unsigned short* __restrict__ Wt, int K, int N) {
    __shared__ float tile[32][33];
    int n0 = blockIdx.x * 32, k0 = blockIdx.y * 32;
    int tx = threadIdx.x & 31, ty = threadIdx.x >> 5; // 32 x 8
#pragma unroll
    for (int i = 0; i < 32; i += 8)
        tile[ty + i][tx] = W[(size_t)(k0 + ty + i) * N + n0 + tx];
    __syncthreads();
#pragma unroll
    for (int i = 0; i < 32; i += 8)
        Wt[(size_t)(n0 + ty + i) * K + k0 + tx] = f2b(tile[tx][ty + i]);
}

// ---------------- LayerNorm: f32 in -> bf16 out, one block per row of 1024 ----------------
__global__ __launch_bounds__(256) void ln_kernel(
    const float* __restrict__ x, const float* __restrict__ w,
    const float* __restrict__ b, unsigned short* __restrict__ out) {
    int row = blockIdx.x;
    int tid = threadIdx.x;
    const float* xr = x + (size_t)row * CDIM;
    float4 v = *(const float4*)(xr + tid * 4);
    float s  = v.x + v.y + v.z + v.w;
    float ss = v.x * v.x + v.y * v.y + v.z * v.z + v.w * v.w;
#pragma unroll
    for (int off = 32; off >= 1; off >>= 1) {
        s  += __shfl_xor(s, off);
        ss += __shfl_xor(ss, off);
    }
    __shared__ float rs[4], rss[4];
    int wave = tid >> 6;
    if ((tid & 63) == 0) { rs[wave] = s; rss[wave] = ss; }
    __syncthreads();
    s  = rs[0] + rs[1] + rs[2] + rs[3];
    ss = rss[0] + rss[1] + rss[2] + rss[3];
    float mean = s * (1.0f / CDIM);
    float var  = ss * (1.0f / CDIM) - mean * mean;
    float rstd = rsqrtf(var + 1e-5f);
    float4 wv = *(const float4*)(w + tid * 4);
    float4 bv = *(const float4*)(b + tid * 4);
    ushort4 o;
    o.x = f2b((v.x - mean) * rstd * wv.x + bv.x);
    o.y = f2b((v.y - mean) * rstd * wv.y + bv.y);
    o.z = f2b((v.z - mean) * rstd * wv.z + bv.z);
    o.w = f2b((v.w - mean) * rstd * wv.w + bv.w);
    *(ushort4*)(out + (size_t)row * CDIM + tid * 4) = o;
}

// ---------------- bf16 MFMA GEMM: C = A[M,K] @ Wt[N,K]^T (+bias, +res, +gelu) ----------
// 128x128 tile, BK=64, 256 threads (4 waves, 2x2), 64x64 per wave, 4x4 frags of 16x16.
template <int MODE>
__global__ __launch_bounds__(256) void gemm_bf16(
    const unsigned short* __restrict__ A, const unsigned short* __restrict__ Wt,
    const float* __restrict__ bias, const float* __restrict__ res,
    void* __restrict__ Cout, int M, int N, int K) {
    __shared__ __align__(16) short As[128 * 64];
    __shared__ __align__(16) short Bs[128 * 64];
    const int tid = threadIdx.x;
    const int lane = tid & 63, w = tid >> 6;
    const int wr = w >> 1, wc = w & 1;
    const int row0 = blockIdx.y * 128, col0 = blockIdx.x * 128;

    const int sr = lane >> 3;                   // 0..7: row within 8-row group
    const int sc = 8 * ((lane & 7) ^ sr);       // element col, pre-swizzled source
    const unsigned short* gA = A  + (size_t)(row0 + w * 8 + sr) * K + sc;
    const unsigned short* gB = Wt + (size_t)(col0 + w * 8 + sr) * K + sc;
    short* ldsA = As + (w * 8) * 64;            // wave-uniform dst base
    short* ldsB = Bs + (w * 8) * 64;

    f32x4 acc[4][4] = {};
    const int h = lane >> 4;                    // 0..3
    const int r15 = lane & 15;

    for (int k0 = 0; k0 < K; k0 += 64) {
        __syncthreads();
#pragma unroll
        for (int i = 0; i < 4; ++i) {
            async_copy16(gA + (size_t)i * 32 * K + k0, ldsA + i * 32 * 64);
            async_copy16(gB + (size_t)i * 32 * K + k0, ldsB + i * 32 * 64);
        }
        __syncthreads();
#pragma unroll
        for (int ks = 0; ks < 2; ++ks) {
            bf16x8 af[4], bfr[4];
#pragma unroll
            for (int i = 0; i < 4; ++i) {
                int ra = wr * 64 + i * 16 + r15;
                int offa = ra * 128 + ((ks * 64 + h * 16) ^ ((ra & 7) << 4));
                af[i] = *(const bf16x8*)((const char*)As + offa);
                int rb = wc * 64 + i * 16 + r15;
                int offb = rb * 128 + ((ks * 64 + h * 16) ^ ((rb & 7) << 4));
                bfr[i] = *(const bf16x8*)((const char*)Bs + offb);
            }
#pragma unroll
            for (int i = 0; i < 4; ++i)
#pragma unroll
                for (int j = 0; j < 4; ++j)
                    acc[i][j] = __builtin_amdgcn_mfma_f32_16x16x32_bf16(
                        af[i], bfr[j], acc[i][j], 0, 0, 0);
        }
    }

#pragma unroll
    for (int i = 0; i < 4; ++i) {
#pragma unroll
        for (int j = 0; j < 4; ++j) {
            int c = col0 + wc * 64 + j * 16 + r15;
            float bv = bias[c];
#pragma unroll
            for (int q = 0; q < 4; ++q) {
                int rr = row0 + wr * 64 + i * 16 + h * 4 + q;
                float v = acc[i][j][q] + bv;
                if (MODE == 2) v = gelu_f(v);
                if (MODE == 1) v += res[(size_t)rr * N + c];
                if (MODE == 1) ((float*)Cout)[(size_t)rr * N + c] = v;
                else ((unsigned short*)Cout)[(size_t)rr * N + c] = f2b(v);
            }
        }
    }
}

// ---------------- MFMA flash attention (bf16 qkv in, bf16 y out) ----------------
// grid = (B*H, T/64), block = 256 (4 waves). Wave w owns q-rows [w*16, w*16+16).
// K staged via global_load_lds (GEMM-identical (row&7) swizzle).
// V staged transposed (Vt[d][kv]) via regs, ((d^(d>>3))&7) swizzle (writes+reads <=2-way).
// P per-wave-local in LDS, ((row^(row>>3))&7) swizzle.
__global__ __launch_bounds__(256) void attn_mfma(
    const unsigned short* __restrict__ qkv, unsigned short* __restrict__ y) {
    const int bh = blockIdx.x;
    const int b = bh >> 4, hh = bh & 15;
    const int qy = gridDim.y - 1 - blockIdx.y;  // longest blocks first
    const int q0 = qy * 64;
    const int tid = threadIdx.x;
    const int lane = tid & 63, w = tid >> 6;
    const int h = lane >> 4, r15 = lane & 15;

    __shared__ __align__(16) short Ks[64 * 64];
    __shared__ __align__(16) short Vt[64 * 64];
    __shared__ __align__(16) short Ps[64 * 64];

    const size_t base = (size_t)b * TDIM * (3 * CDIM);
    const unsigned short* qb = qkv + base + hh * DH;
    const unsigned short* kb = qkv + base + CDIM + hh * DH;
    const unsigned short* vb = qkv + base + 2 * CDIM + hh * DH;

    // Q fragments (A-frag), loaded once: rows q0 + w*16 + r15, d = ks*32 + h*8
    bf16x8 aq[2];
#pragma unroll
    for (int ks = 0; ks < 2; ++ks)
        aq[ks] = *(const bf16x8*)(qb + (size_t)(q0 + w * 16 + r15) * (3 * CDIM) +
                                  ks * 32 + h * 8);

    // K staging geometry: per wave 2 insts x 8 rows; source col pre-swizzled by row&7
    const int sr = lane >> 3;
    const int scK = 8 * ((lane & 7) ^ sr);
    // V reg staging: thread handles kv row rV(+32), d-block dblk..dblk+8
    const int rV = tid >> 3;
    const int dblk = (tid & 7) * 8;

    f32x4 oacc[4] = {};                  // oacc[j2][q]: O[w*16+h*4+q][j2*16+r15]
    float mreg[4], lreg[4];
#pragma unroll
    for (int q = 0; q < 4; ++q) { mreg[q] = -1e30f; lreg[q] = 0.f; }

    for (int kt = 0; kt <= qy; ++kt) {
        const int kv0 = kt * 64;
        __syncthreads();  // previous tile's K/V reads complete
        // --- stage K tile ---
#pragma unroll
        for (int i = 0; i < 2; ++i) {
            int rowbase = w * 16 + i * 8;
            async_copy16(kb + (size_t)(kv0 + rowbase + sr) * (3 * CDIM) + scK,
                         Ks + rowbase * 64);
        }
        // --- stage V transposed ---
#pragma unroll
        for (int rd = 0; rd < 2; ++rd) {
            int r = rV + rd * 32;
            bf16x8 vv = *(const bf16x8*)(vb + (size_t)(kv0 + r) * (3 * CDIM) + dblk);
#pragma unroll
            for (int j = 0; j < 8; ++j) {
                int d = dblk + j;
                int off = d * 128 + ((2 * r) ^ (((d ^ (d >> 3)) & 7) << 4));
                *(short*)((char*)Vt + off) = vv[j];
            }
        }
        __syncthreads();  // K + Vt visible

        // --- S = Q K^T : sacc[j] covers cols j*16+r15, rows h*4+q (wave-local) ---
        f32x4 sacc[4] = {};
#pragma unroll
        for (int ks = 0; ks < 2; ++ks) {
#pragma unroll
            for (int j = 0; j < 4; ++j) {
                int rb = j * 16 + r15;
                int off = rb * 128 + ((ks * 64 + h * 16) ^ ((rb & 7) << 4));
                bf16x8 kf = *(const bf16x8*)((const char*)Ks + off);
                sacc[j] = __builtin_amdgcn_mfma_f32_16x16x32_bf16(aq[ks], kf, sacc[j], 0, 0, 0);
            }
        }

        // --- scale + causal mask ---
        float sv[4][4]; // [q][j]
        const bool diag = (kt == qy);
#pragma unroll
        for (int q = 0; q < 4; ++q) {
            int rloc = w * 16 + h * 4 + q;  // row within 64-tile
#pragma unroll
            for (int j = 0; j < 4; ++j) {
                float v = sacc[j][q] * 0.125f;
                if (diag && (j * 16 + r15) > rloc) v = -1e30f;
                sv[q][j] = v;
            }
        }

        // --- online softmax (rows live across 16 lanes x 4 regs) ---
        float sf[4];
#pragma unroll
        for (int q = 0; q < 4; ++q) {
            float pm = fmaxf(fmaxf(sv[q][0], sv[q][1]), fmaxf(sv[q][2], sv[q][3]));
#pragma unroll
            for (int off = 1; off < 16; off <<= 1) pm = fmaxf(pm, __shfl_xor(pm, off));
            float mnew = fmaxf(mreg[q], pm);
            sf[q] = expf(mreg[q] - mnew);
            float rsum = 0.f;
#pragma unroll
            for (int j = 0; j < 4; ++j) {
                float p = expf(sv[q][j] - mnew);
                sv[q][j] = p;
                rsum += p;
            }
#pragma unroll
            for (int off = 1; off < 16; off <<= 1) rsum += __shfl_xor(rsum, off);
            lreg[q] = lreg[q] * sf[q] + rsum;
            mreg[q] = mnew;
        }
        // rescale O
#pragma unroll
        for (int j2 = 0; j2 < 4; ++j2)
#pragma unroll
            for (int q = 0; q < 4; ++q) oacc[j2][q] *= sf[q];

        // --- write P (bf16) to wave-local LDS rows ---
#pragma unroll
        for (int q = 0; q < 4; ++q) {
            int row = w * 16 + h * 4 + q;
            int swz = ((row ^ (row >> 3)) & 7) << 4;
#pragma unroll
            for (int j = 0; j < 4; ++j) {
                int off = row * 128 + ((j * 32 + 2 * r15) ^ swz);
                *(short*)((char*)Ps + off) = (short)f2b(sv[q][j]);
            }
        }
        asm volatile("s_waitcnt lgkmcnt(0)" ::: "memory");
        __builtin_amdgcn_sched_barrier(0);

        // --- O += P @ V ---
#pragma unroll
        for (int ks = 0; ks < 2; ++ks) {
            int prow = w * 16 + r15;
            int poff = prow * 128 +
                       ((ks * 64 + h * 16) ^ (((prow ^ (prow >> 3)) & 7) << 4));
            bf16x8 pa = *(const bf16x8*)((const char*)Ps + poff);
#pragma unroll
            for (int j2 = 0; j2 < 4; ++j2) {
                int d = j2 * 16 + r15;
                int voff = d * 128 + ((ks * 64 + h * 16) ^ (((d ^ (d >> 3)) & 7) << 4));
                bf16x8 vf = *(const bf16x8*)((const char*)Vt + voff);
                oacc[j2] = __builtin_amdgcn_mfma_f32_16x16x32_bf16(pa, vf, oacc[j2], 0, 0, 0);
            }
        }
    }

    // --- epilogue: y[b, q0 + w*16 + h*4 + q][hh*64 + j2*16 + r15] ---
#pragma unroll
    for (int q = 0; q < 4; ++q) {
        float inv = 1.0f / lreg[q];
        int grow = q0 + w * 16 + h * 4 + q;
#pragma unroll
        for (int j2 = 0; j2 < 4; ++j2) {
            y[(size_t)(b * TDIM + grow) * CDIM + hh * DH + j2 * 16 + r15] =
                f2b(oacc[j2][q] * inv);
        }
    }
}

// ---------------- launch ----------------
extern "C" void kernel_launch(void* const* d_in, const int* in_sizes, int n_in,
                              void* d_out, int out_size, void* d_ws, size_t ws_size,
                              hipStream_t stream) {
    const float* x      = (const float*)d_in[0];
    const float* ln1_w  = (const float*)d_in[1];
    const float* ln1_b  = (const float*)d_in[2];
    const float* W_attn = (const float*)d_in[3];
    const float* b_attn = (const float*)d_in[4];
    const float* W_o    = (const float*)d_in[5];
    const float* b_o    = (const float*)d_in[6];
    const float* ln2_w  = (const float*)d_in[7];
    const float* ln2_b  = (const float*)d_in[8];
    const float* W_fc   = (const float*)d_in[9];
    const float* b_fc   = (const float*)d_in[10];
    const float* W_proj = (const float*)d_in[11];
    const float* b_proj = (const float*)d_in[12];
    float* out = (float*)d_out;

    char* ws = (char*)d_ws;
    const size_t MB = 1024 * 1024;
    unsigned short* h_bf    = (unsigned short*)(ws);             // 8 MB  [4096,1024]
    unsigned short* big     = (unsigned short*)(ws + 8 * MB);    // 32 MB qkv / fcact
    unsigned short* Wt_attn = (unsigned short*)(ws + 40 * MB);   // 6 MB  [3072,1024]
    unsigned short* Wt_o    = (unsigned short*)(ws + 46 * MB);   // 2 MB  [1024,1024]
    unsigned short* Wt_fc   = (unsigned short*)(ws + 48 * MB);   // 8 MB  [4096,1024]
    unsigned short* Wt_proj = (unsigned short*)(ws + 56 * MB);   // 8 MB  [1024,4096]
    float* x1 = out;

    // 0. weight transpose + cast (W[K][N] -> Wt[N][K] bf16)
    hipLaunchKernelGGL(transpose_cast, dim3(96, 32),  dim3(256), 0, stream, W_attn, Wt_attn, CDIM, 3 * CDIM);
    hipLaunchKernelGGL(transpose_cast, dim3(32, 32),  dim3(256), 0, stream, W_o,    Wt_o,    CDIM, CDIM);
    hipLaunchKernelGGL(transpose_cast, dim3(128, 32), dim3(256), 0, stream, W_fc,   Wt_fc,   CDIM, 4 * CDIM);
    hipLaunchKernelGGL(transpose_cast, dim3(32, 128), dim3(256), 0, stream, W_proj, Wt_proj, 4 * CDIM, CDIM);

    // 1. h = LN1(x)  (bf16)
    hipLaunchKernelGGL(ln_kernel, dim3(MDIM), dim3(256), 0, stream, x, ln1_w, ln1_b, h_bf);
    // 2. qkv = h @ W_attn + b_attn  -> bf16 [4096, 3072]
    hipLaunchKernelGGL((gemm_bf16<0>), dim3(3 * CDIM / 128, MDIM / 128), dim3(256), 0,
                       stream, h_bf, Wt_attn, b_attn, nullptr, big, MDIM, 3 * CDIM, CDIM);
    // 3. y = attention(qkv) -> h_bf (bf16)
    hipLaunchKernelGGL(attn_mfma, dim3(BDIM * HEADS, TDIM / 64), dim3(256), 0, stream,
                       big, h_bf);
    // 4. x1 = x + y @ W_o + b_o  (f32)
    hipLaunchKernelGGL((gemm_bf16<1>), dim3(CDIM / 128, MDIM / 128), dim3(256), 0,
                       stream, h_bf, Wt_o, b_o, x, x1, MDIM, CDIM, CDIM);
    // 5. h = LN2(x1) (bf16)
    hipLaunchKernelGGL(ln_kernel, dim3(MDIM), dim3(256), 0, stream, x1, ln2_w, ln2_b, h_bf);
    // 6. fcact = gelu(h @ W_fc + b_fc) -> bf16 [4096, 4096]
    hipLaunchKernelGGL((gemm_bf16<2>), dim3(4 * CDIM / 128, MDIM / 128), dim3(256), 0,
                       stream, h_bf, Wt_fc, b_fc, nullptr, big, MDIM, 4 * CDIM, CDIM);
    // 7. out = x1 + fcact @ W_proj + b_proj (f32)
    hipLaunchKernelGGL((gemm_bf16<1>), dim3(CDIM / 128, MDIM / 128), dim3(256), 0,
                       stream, big, Wt_proj, b_proj, x1, out, MDIM, CDIM, 4 * CDIM);
}

// Round 4
// 340.366 us; speedup vs baseline: 5.8852x; 1.1938x over previous
//
#include <hip/hip_runtime.h>
#include <math.h>

// GPT-2 block forward. bf16 MFMA GEMMs + bf16 MFMA flash attention (32x32, in-reg softmax).
// B=2, T=2048, C=1024, H=16, Dh=64. M = B*T = 4096.
constexpr int TDIM = 2048;
constexpr int BDIM = 2;
constexpr int CDIM = 1024;
constexpr int HEADS = 16;
constexpr int DH = 64;
constexpr int MDIM = BDIM * TDIM; // 4096

typedef short bf16x8 __attribute__((ext_vector_type(8)));
typedef float f32x4 __attribute__((ext_vector_type(4)));
typedef float f32x16 __attribute__((ext_vector_type(16)));

__device__ __forceinline__ float b2f(unsigned short u) {
    union { float f; unsigned int i; } v; v.i = ((unsigned int)u) << 16; return v.f;
}
__device__ __forceinline__ unsigned short f2b(float f) {
    union { float f; unsigned int i; } v; v.f = f;
    unsigned int r = (v.i + 0x7FFFu + ((v.i >> 16) & 1u)) >> 16;
    return (unsigned short)r;
}
__device__ __forceinline__ unsigned int pk2(float lo, float hi) {
    return ((unsigned int)f2b(hi) << 16) | (unsigned int)f2b(lo);
}
__device__ __forceinline__ float gelu_f(float x) {
    const float c0 = 0.7978845608028654f; // sqrt(2/pi)
    float x3 = x * x * x;
    float t = tanhf(c0 * (x + 0.044715f * x3));
    return 0.5f * x * (1.0f + t);
}
__device__ __forceinline__ void async_copy16(const void* g, void* l) {
    __builtin_amdgcn_global_load_lds(
        (const __attribute__((address_space(1))) unsigned int*)g,
        (__attribute__((address_space(3))) unsigned int*)l, 16, 0, 0);
}

// ---------------- weight transpose + cast: W[K][N] f32 -> Wt[N][K] bf16 ----------------
__global__ __launch_bounds__(256) void transpose_cast(
    const float* __restrict__ W, unsigned short* __restrict__ Wt, int K, int N) {
    __shared__ float tile[32][33];
    int n0 = blockIdx.x * 32, k0 = blockIdx.y * 32;
    int tx = threadIdx.x & 31, ty = threadIdx.x >> 5; // 32 x 8
#pragma unroll
    for (int i = 0; i < 32; i += 8)
        tile[ty + i][tx] = W[(size_t)(k0 + ty + i) * N + n0 + tx];
    __syncthreads();
#pragma unroll
    for (int i = 0; i < 32; i += 8)
        Wt[(size_t)(n0 + ty + i) * K + k0 + tx] = f2b(tile[tx][ty + i]);
}

// ---------------- LayerNorm: f32 in -> bf16 out, one block per row of 1024 ----------------
__global__ __launch_bounds__(256) void ln_kernel(
    const float* __restrict__ x, const float* __restrict__ w,
    const float* __restrict__ b, unsigned short* __restrict__ out) {
    int row = blockIdx.x;
    int tid = threadIdx.x;
    const float* xr = x + (size_t)row * CDIM;
    float4 v = *(const float4*)(xr + tid * 4);
    float s  = v.x + v.y + v.z + v.w;
    float ss = v.x * v.x + v.y * v.y + v.z * v.z + v.w * v.w;
#pragma unroll
    for (int off = 32; off >= 1; off >>= 1) {
        s  += __shfl_xor(s, off);
        ss += __shfl_xor(ss, off);
    }
    __shared__ float rs[4], rss[4];
    int wave = tid >> 6;
    if ((tid & 63) == 0) { rs[wave] = s; rss[wave] = ss; }
    __syncthreads();
    s  = rs[0] + rs[1] + rs[2] + rs[3];
    ss = rss[0] + rss[1] + rss[2] + rss[3];
    float mean = s * (1.0f / CDIM);
    float var  = ss * (1.0f / CDIM) - mean * mean;
    float rstd = rsqrtf(var + 1e-5f);
    float4 wv = *(const float4*)(w + tid * 4);
    float4 bv = *(const float4*)(b + tid * 4);
    ushort4 o;
    o.x = f2b((v.x - mean) * rstd * wv.x + bv.x);
    o.y = f2b((v.y - mean) * rstd * wv.y + bv.y);
    o.z = f2b((v.z - mean) * rstd * wv.z + bv.z);
    o.w = f2b((v.w - mean) * rstd * wv.w + bv.w);
    *(ushort4*)(out + (size_t)row * CDIM + tid * 4) = o;
}

// ---------------- bf16 MFMA GEMM: C = A[M,K] @ Wt[N,K]^T (+bias, +res, +gelu) ----------
// 128x128 tile, BK=64, 256 threads (4 waves, 2x2), 64x64 per wave, 4x4 frags of 16x16.
template <int MODE>
__global__ __launch_bounds__(256) void gemm_bf16(
    const unsigned short* __restrict__ A, const unsigned short* __restrict__ Wt,
    const float* __restrict__ bias, const float* __restrict__ res,
    void* __restrict__ Cout, int M, int N, int K) {
    __shared__ __align__(16) short As[128 * 64];
    __shared__ __align__(16) short Bs[128 * 64];
    const int tid = threadIdx.x;
    const int lane = tid & 63, w = tid >> 6;
    const int wr = w >> 1, wc = w & 1;
    const int row0 = blockIdx.y * 128, col0 = blockIdx.x * 128;

    const int sr = lane >> 3;                   // 0..7: row within 8-row group
    const int sc = 8 * ((lane & 7) ^ sr);       // element col, pre-swizzled source
    const unsigned short* gA = A  + (size_t)(row0 + w * 8 + sr) * K + sc;
    const unsigned short* gB = Wt + (size_t)(col0 + w * 8 + sr) * K + sc;
    short* ldsA = As + (w * 8) * 64;            // wave-uniform dst base
    short* ldsB = Bs + (w * 8) * 64;

    f32x4 acc[4][4] = {};
    const int h = lane >> 4;                    // 0..3
    const int r15 = lane & 15;

    for (int k0 = 0; k0 < K; k0 += 64) {
        __syncthreads();
#pragma unroll
        for (int i = 0; i < 4; ++i) {
            async_copy16(gA + (size_t)i * 32 * K + k0, ldsA + i * 32 * 64);
            async_copy16(gB + (size_t)i * 32 * K + k0, ldsB + i * 32 * 64);
        }
        __syncthreads();
#pragma unroll
        for (int ks = 0; ks < 2; ++ks) {
            bf16x8 af[4], bfr[4];
#pragma unroll
            for (int i = 0; i < 4; ++i) {
                int ra = wr * 64 + i * 16 + r15;
                int offa = ra * 128 + ((ks * 64 + h * 16) ^ ((ra & 7) << 4));
                af[i] = *(const bf16x8*)((const char*)As + offa);
                int rb = wc * 64 + i * 16 + r15;
                int offb = rb * 128 + ((ks * 64 + h * 16) ^ ((rb & 7) << 4));
                bfr[i] = *(const bf16x8*)((const char*)Bs + offb);
            }
#pragma unroll
            for (int i = 0; i < 4; ++i)
#pragma unroll
                for (int j = 0; j < 4; ++j)
                    acc[i][j] = __builtin_amdgcn_mfma_f32_16x16x32_bf16(
                        af[i], bfr[j], acc[i][j], 0, 0, 0);
        }
    }

#pragma unroll
    for (int i = 0; i < 4; ++i) {
#pragma unroll
        for (int j = 0; j < 4; ++j) {
            int c = col0 + wc * 64 + j * 16 + r15;
            float bv = bias[c];
#pragma unroll
            for (int q = 0; q < 4; ++q) {
                int rr = row0 + wr * 64 + i * 16 + h * 4 + q;
                float v = acc[i][j][q] + bv;
                if (MODE == 2) v = gelu_f(v);
                if (MODE == 1) v += res[(size_t)rr * N + c];
                if (MODE == 1) ((float*)Cout)[(size_t)rr * N + c] = v;
                else ((unsigned short*)Cout)[(size_t)rr * N + c] = f2b(v);
            }
        }
    }
}

// ---------------- MFMA flash attention, 32x32 swapped-QK^T, in-register softmax --------
// grid = (B*H, T/128), block = 256 (4 waves). qy = 15 - blockIdx.y (LPT: longest first).
// Wave w owns q rows [q0 + 32w, q0 + 32w + 32). Per lane: q = q0 + 32w + (lane&31) FIXED.
// S^T = mfma(K, Q): lane holds 16 P values of ITS q row per 32-kv subtile.
// O^T = mfma(V^T, P^T): accumulator col = q (lane-fixed) -> m/l/rescale pure per-lane.
// P fixup to B-frags: bf16 pack + 8 shfl_xor(32) word swaps per 64-tile.
__global__ __launch_bounds__(256) void attn_mfma(
    const unsigned short* __restrict__ qkv, unsigned short* __restrict__ y) {
    const int bh = blockIdx.x;
    const int b = bh >> 4, hh = bh & 15;
    const int qy = (int)gridDim.y - 1 - blockIdx.y;
    const int q0 = qy * 128;
    const int tid = threadIdx.x;
    const int lane = tid & 63, w = tid >> 6;
    const int hi = lane >> 5, q31 = lane & 31;

    // LDS: K[64 kv][64 d] (8KB) + Vt[64 d][64 kv] (8KB); Os[128][68] f32 aliases both
    __shared__ __align__(16) char smem[128 * 68 * 4];
    short* Ks = (short*)smem;
    short* Vt = (short*)(smem + 8192);
    float (*Os)[68] = (float (*)[68])smem;

    const size_t base = (size_t)b * TDIM * (3 * CDIM);
    const unsigned short* qb = qkv + base + hh * DH;
    const unsigned short* kb = qkv + base + CDIM + hh * DH;
    const unsigned short* vb = qkv + base + 2 * CDIM + hh * DH;

    const int gq = q0 + w * 32 + q31;       // this lane's q row (global, within T)
    const int qmin_w = q0 + w * 32;
    const int qmax_w = qmin_w + 31;

    // Q B-frags: qf[ks] elem j = Q[gq][16*ks + 8*hi + j]
    bf16x8 qf[4];
#pragma unroll
    for (int ks = 0; ks < 4; ++ks)
        qf[ks] = *(const bf16x8*)(qb + (size_t)gq * (3 * CDIM) + ks * 16 + hi * 8);

    // staging geometry
    const int sr = lane >> 3;
    const int scK = 8 * ((lane & 7) ^ sr);  // pre-swizzled source col (elems)
    const int rV = tid >> 3;                // 0..31 kv row (+32)
    const int dblk = (tid & 7) * 8;

    f32x16 oacc[2] = {};                    // O^T: oacc[j2][r] = O[q][d=32*j2+(r&3)+8*(r>>2)+4*hi]
    float m = -1e30f, l = 0.f;

    const int NT = 2 * qy + 2;
    for (int kt = 0; kt < NT; ++kt) {
        const int kv0 = kt * 64;
        __syncthreads();
        // --- stage K tile (rows w*16..w*16+15) ---
#pragma unroll
        for (int i = 0; i < 2; ++i) {
            int rowbase = w * 16 + i * 8;
            async_copy16(kb + (size_t)(kv0 + rowbase + sr) * (3 * CDIM) + scK,
                         Ks + rowbase * 64);
        }
        // --- stage V transposed: Vt[d][kv], swizzle ((d^(d>>3))&7)<<4 ---
#pragma unroll
        for (int rd = 0; rd < 2; ++rd) {
            int r = rV + rd * 32;
            bf16x8 vv = *(const bf16x8*)(vb + (size_t)(kv0 + r) * (3 * CDIM) + dblk);
#pragma unroll
            for (int j = 0; j < 8; ++j) {
                int d = dblk + j;
                int off = d * 128 + ((2 * r) ^ (((d ^ (d >> 3)) & 7) << 4));
                *(short*)((char*)Vt + off) = vv[j];
            }
        }
        __syncthreads();

#pragma unroll
        for (int sub = 0; sub < 2; ++sub) {
            const int kvs = kv0 + sub * 32;
            if (kvs > qmax_w) break;        // wave-uniform

            // --- S^T subtile: rows kv (reg-mapped), col q (lane) ---
            f32x16 sacc = {};
#pragma unroll
            for (int ks = 0; ks < 4; ++ks) {
                int row = sub * 32 + q31;
                int off = row * 128 + ((32 * ks + 16 * hi) ^ ((row & 7) << 4));
                bf16x8 kf = *(const bf16x8*)((const char*)Ks + off);
                sacc = __builtin_amdgcn_mfma_f32_32x32x16_bf16(kf, qf[ks], sacc, 0, 0, 0);
            }

            // --- scale + causal mask (p[r]: kv = kvs + (r&3)+8*(r>>2)+4*hi) ---
            float p[16];
            if (kvs + 31 > qmin_w) {
#pragma unroll
                for (int r = 0; r < 16; ++r) {
                    int kvg = kvs + (r & 3) + 8 * (r >> 2) + 4 * hi;
                    p[r] = (kvg > gq) ? -1e30f : sacc[r] * 0.125f;
                }
            } else {
#pragma unroll
                for (int r = 0; r < 16; ++r) p[r] = sacc[r] * 0.125f;
            }

            // --- per-lane online softmax ---
            float t8[8];
#pragma unroll
            for (int r = 0; r < 8; ++r) t8[r] = fmaxf(p[r], p[r + 8]);
#pragma unroll
            for (int r = 0; r < 4; ++r) t8[r] = fmaxf(t8[r], t8[r + 4]);
            float pm = fmaxf(fmaxf(t8[0], t8[1]), fmaxf(t8[2], t8[3]));
            pm = fmaxf(pm, __shfl_xor(pm, 32));
            float mnew = fmaxf(m, pm);
            float sf = expf(m - mnew);
#pragma unroll
            for (int r = 0; r < 16; ++r) p[r] = expf(p[r] - mnew);
#pragma unroll
            for (int r = 0; r < 8; ++r) t8[r] = p[r] + p[r + 8];
#pragma unroll
            for (int r = 0; r < 4; ++r) t8[r] = t8[r] + t8[r + 4];
            float rsum = (t8[0] + t8[1]) + (t8[2] + t8[3]);
            rsum += __shfl_xor(rsum, 32);
            l = l * sf + rsum;
            m = mnew;
            oacc[0] *= sf;
            oacc[1] *= sf;

            // --- pack P -> PV B-frags (per 16-kv slice ks2) ---
            bf16x8 pa[2];
#pragma unroll
            for (int k2 = 0; k2 < 2; ++k2) {
                unsigned int A0 = pk2(p[8 * k2 + 0], p[8 * k2 + 1]);
                unsigned int A1 = pk2(p[8 * k2 + 2], p[8 * k2 + 3]);
                unsigned int B0 = pk2(p[8 * k2 + 4], p[8 * k2 + 5]);
                unsigned int B1 = pk2(p[8 * k2 + 6], p[8 * k2 + 7]);
                unsigned int sA0 = __shfl_xor((int)A0, 32);
                unsigned int sA1 = __shfl_xor((int)A1, 32);
                unsigned int sB0 = __shfl_xor((int)B0, 32);
                unsigned int sB1 = __shfl_xor((int)B1, 32);
                union { int i[4]; bf16x8 h; } u;
                u.i[0] = hi ? (int)sB0 : (int)A0;
                u.i[1] = hi ? (int)sB1 : (int)A1;
                u.i[2] = hi ? (int)B0 : (int)sA0;
                u.i[3] = hi ? (int)B1 : (int)sA1;
                pa[k2] = u.h;
            }

            // --- O^T += V^T @ P^T ---
#pragma unroll
            for (int j2 = 0; j2 < 2; ++j2) {
                int row = 32 * j2 + q31;    // d row
                int swz = ((row ^ (row >> 3)) & 7) << 4;
#pragma unroll
                for (int k2 = 0; k2 < 2; ++k2) {
                    int off = row * 128 + ((64 * sub + 32 * k2 + 16 * hi) ^ swz);
                    bf16x8 vf = *(const bf16x8*)((const char*)Vt + off);
                    oacc[j2] = __builtin_amdgcn_mfma_f32_32x32x16_bf16(vf, pa[k2], oacc[j2], 0, 0, 0);
                }
            }
        }
    }

    // --- epilogue: transpose O^T through LDS, coalesced bf16 store ---
    __syncthreads();                         // all K/V reads done; Os aliases them
    float invl = 1.0f / l;
#pragma unroll
    for (int j2 = 0; j2 < 2; ++j2)
#pragma unroll
        for (int g = 0; g < 4; ++g) {
            float4 v4 = make_float4(oacc[j2][4 * g + 0] * invl, oacc[j2][4 * g + 1] * invl,
                                    oacc[j2][4 * g + 2] * invl, oacc[j2][4 * g + 3] * invl);
            *(float4*)&Os[w * 32 + q31][32 * j2 + 8 * g + 4 * hi] = v4;
        }
    __syncthreads();
#pragma unroll
    for (int it = 0; it < 8; ++it) {
        int row = w * 32 + it * 4 + (lane >> 4);
        int col = (lane & 15) * 4;
        float4 v = *(const float4*)&Os[row][col];
        ushort4 o;
        o.x = f2b(v.x); o.y = f2b(v.y); o.z = f2b(v.z); o.w = f2b(v.w);
        *(ushort4*)(y + (size_t)(b * TDIM + q0 + row) * CDIM + hh * DH + col) = o;
    }
}

// ---------------- launch ----------------
extern "C" void kernel_launch(void* const* d_in, const int* in_sizes, int n_in,
                              void* d_out, int out_size, void* d_ws, size_t ws_size,
                              hipStream_t stream) {
    const float* x      = (const float*)d_in[0];
    const float* ln1_w  = (const float*)d_in[1];
    const float* ln1_b  = (const float*)d_in[2];
    const float* W_attn = (const float*)d_in[3];
    const float* b_attn = (const float*)d_in[4];
    const float* W_o    = (const float*)d_in[5];
    const float* b_o    = (const float*)d_in[6];
    const float* ln2_w  = (const float*)d_in[7];
    const float* ln2_b  = (const float*)d_in[8];
    const float* W_fc   = (const float*)d_in[9];
    const float* b_fc   = (const float*)d_in[10];
    const float* W_proj = (const float*)d_in[11];
    const float* b_proj = (const float*)d_in[12];
    float* out = (float*)d_out;

    char* ws = (char*)d_ws;
    const size_t MB = 1024 * 1024;
    unsigned short* h_bf    = (unsigned short*)(ws);             // 8 MB  [4096,1024]
    unsigned short* big     = (unsigned short*)(ws + 8 * MB);    // 32 MB qkv / fcact
    unsigned short* Wt_attn = (unsigned short*)(ws + 40 * MB);   // 6 MB  [3072,1024]
    unsigned short* Wt_o    = (unsigned short*)(ws + 46 * MB);   // 2 MB  [1024,1024]
    unsigned short* Wt_fc   = (unsigned short*)(ws + 48 * MB);   // 8 MB  [4096,1024]
    unsigned short* Wt_proj = (unsigned short*)(ws + 56 * MB);   // 8 MB  [1024,4096]
    float* x1 = out;

    // 0. weight transpose + cast (W[K][N] -> Wt[N][K] bf16)
    hipLaunchKernelGGL(transpose_cast, dim3(96, 32),  dim3(256), 0, stream, W_attn, Wt_attn, CDIM, 3 * CDIM);
    hipLaunchKernelGGL(transpose_cast, dim3(32, 32),  dim3(256), 0, stream, W_o,    Wt_o,    CDIM, CDIM);
    hipLaunchKernelGGL(transpose_cast, dim3(128, 32), dim3(256), 0, stream, W_fc,   Wt_fc,   CDIM, 4 * CDIM);
    hipLaunchKernelGGL(transpose_cast, dim3(32, 128), dim3(256), 0, stream, W_proj, Wt_proj, 4 * CDIM, CDIM);

    // 1. h = LN1(x)  (bf16)
    hipLaunchKernelGGL(ln_kernel, dim3(MDIM), dim3(256), 0, stream, x, ln1_w, ln1_b, h_bf);
    // 2. qkv = h @ W_attn + b_attn  -> bf16 [4096, 3072]
    hipLaunchKernelGGL((gemm_bf16<0>), dim3(3 * CDIM / 128, MDIM / 128), dim3(256), 0,
                       stream, h_bf, Wt_attn, b_attn, nullptr, big, MDIM, 3 * CDIM, CDIM);
    // 3. y = attention(qkv) -> h_bf (bf16)
    hipLaunchKernelGGL(attn_mfma, dim3(BDIM * HEADS, TDIM / 128), dim3(256), 0, stream,
                       big, h_bf);
    // 4. x1 = x + y @ W_o + b_o  (f32)
    hipLaunchKernelGGL((gemm_bf16<1>), dim3(CDIM / 128, MDIM / 128), dim3(256), 0,
                       stream, h_bf, Wt_o, b_o, x, x1, MDIM, CDIM, CDIM);
    // 5. h = LN2(x1) (bf16)
    hipLaunchKernelGGL(ln_kernel, dim3(MDIM), dim3(256), 0, stream, x1, ln2_w, ln2_b, h_bf);
    // 6. fcact = gelu(h @ W_fc + b_fc) -> bf16 [4096, 4096]
    hipLaunchKernelGGL((gemm_bf16<2>), dim3(4 * CDIM / 128, MDIM / 128), dim3(256), 0,
                       stream, h_bf, Wt_fc, b_fc, nullptr, big, MDIM, 4 * CDIM, CDIM);
    // 7. out = x1 + fcact @ W_proj + b_proj (f32)
    hipLaunchKernelGGL((gemm_bf16<1>), dim3(CDIM / 128, MDIM / 128), dim3(256), 0,
                       stream, big, Wt_proj, b_proj, x1, out, MDIM, CDIM, 4 * CDIM);
}

// Round 5
// 320.994 us; speedup vs baseline: 6.2404x; 1.0603x over previous
//
#include <hip/hip_runtime.h>
#include <math.h>

// GPT-2 block forward. bf16 MFMA GEMMs + bf16 MFMA flash attention (32x32, in-reg softmax).
// B=2, T=2048, C=1024, H=16, Dh=64. M = B*T = 4096.
constexpr int TDIM = 2048;
constexpr int BDIM = 2;
constexpr int CDIM = 1024;
constexpr int HEADS = 16;
constexpr int DH = 64;
constexpr int MDIM = BDIM * TDIM; // 4096

typedef short bf16x8 __attribute__((ext_vector_type(8)));
typedef float f32x4 __attribute__((ext_vector_type(4)));
typedef float f32x16 __attribute__((ext_vector_type(16)));

__device__ __forceinline__ float b2f(unsigned short u) {
    union { float f; unsigned int i; } v; v.i = ((unsigned int)u) << 16; return v.f;
}
__device__ __forceinline__ unsigned short f2b(float f) {
    union { float f; unsigned int i; } v; v.f = f;
    unsigned int r = (v.i + 0x7FFFu + ((v.i >> 16) & 1u)) >> 16;
    return (unsigned short)r;
}
// HW packed f32x2 -> bf16x2 (RNE), single instruction; no builtin on gfx950.
__device__ __forceinline__ unsigned int cvtpk(float lo, float hi) {
    unsigned int r;
    asm("v_cvt_pk_bf16_f32 %0, %1, %2" : "=v"(r) : "v"(lo), "v"(hi));
    return r;
}
__device__ __forceinline__ float gelu_f(float x) {
    const float c0 = 0.7978845608028654f; // sqrt(2/pi)
    float x3 = x * x * x;
    float t = tanhf(c0 * (x + 0.044715f * x3));
    return 0.5f * x * (1.0f + t);
}
__device__ __forceinline__ void async_copy16(const void* g, void* l) {
    __builtin_amdgcn_global_load_lds(
        (const __attribute__((address_space(1))) unsigned int*)g,
        (__attribute__((address_space(3))) unsigned int*)l, 16, 0, 0);
}

// ---------------- weight transpose + cast: W[K][N] f32 -> Wt[N][K] bf16 ----------------
__global__ __launch_bounds__(256) void transpose_cast(
    const float* __restrict__ W, unsigned short* __restrict__ Wt, int K, int N) {
    __shared__ float tile[32][33];
    int n0 = blockIdx.x * 32, k0 = blockIdx.y * 32;
    int tx = threadIdx.x & 31, ty = threadIdx.x >> 5; // 32 x 8
#pragma unroll
    for (int i = 0; i < 32; i += 8)
        tile[ty + i][tx] = W[(size_t)(k0 + ty + i) * N + n0 + tx];
    __syncthreads();
#pragma unroll
    for (int i = 0; i < 32; i += 8)
        Wt[(size_t)(n0 + ty + i) * K + k0 + tx] = f2b(tile[tx][ty + i]);
}

// ---------------- LayerNorm: f32 in -> bf16 out, one block per row of 1024 ----------------
__global__ __launch_bounds__(256) void ln_kernel(
    const float* __restrict__ x, const float* __restrict__ w,
    const float* __restrict__ b, unsigned short* __restrict__ out) {
    int row = blockIdx.x;
    int tid = threadIdx.x;
    const float* xr = x + (size_t)row * CDIM;
    float4 v = *(const float4*)(xr + tid * 4);
    float s  = v.x + v.y + v.z + v.w;
    float ss = v.x * v.x + v.y * v.y + v.z * v.z + v.w * v.w;
#pragma unroll
    for (int off = 32; off >= 1; off >>= 1) {
        s  += __shfl_xor(s, off);
        ss += __shfl_xor(ss, off);
    }
    __shared__ float rs[4], rss[4];
    int wave = tid >> 6;
    if ((tid & 63) == 0) { rs[wave] = s; rss[wave] = ss; }
    __syncthreads();
    s  = rs[0] + rs[1] + rs[2] + rs[3];
    ss = rss[0] + rss[1] + rss[2] + rss[3];
    float mean = s * (1.0f / CDIM);
    float var  = ss * (1.0f / CDIM) - mean * mean;
    float rstd = rsqrtf(var + 1e-5f);
    float4 wv = *(const float4*)(w + tid * 4);
    float4 bv = *(const float4*)(b + tid * 4);
    ushort4 o;
    o.x = f2b((v.x - mean) * rstd * wv.x + bv.x);
    o.y = f2b((v.y - mean) * rstd * wv.y + bv.y);
    o.z = f2b((v.z - mean) * rstd * wv.z + bv.z);
    o.w = f2b((v.w - mean) * rstd * wv.w + bv.w);
    *(ushort4*)(out + (size_t)row * CDIM + tid * 4) = o;
}

// ---------------- bf16 MFMA GEMM: C = A[M,K] @ Wt[N,K]^T (+bias, +res, +gelu) ----------
// 128x128 tile, BK=64, 256 threads (4 waves, 2x2), 64x64 per wave, 4x4 frags of 16x16.
template <int MODE>
__global__ __launch_bounds__(256) void gemm_bf16(
    const unsigned short* __restrict__ A, const unsigned short* __restrict__ Wt,
    const float* __restrict__ bias, const float* __restrict__ res,
    void* __restrict__ Cout, int M, int N, int K) {
    __shared__ __align__(16) short As[128 * 64];
    __shared__ __align__(16) short Bs[128 * 64];
    const int tid = threadIdx.x;
    const int lane = tid & 63, w = tid >> 6;
    const int wr = w >> 1, wc = w & 1;
    const int row0 = blockIdx.y * 128, col0 = blockIdx.x * 128;

    const int sr = lane >> 3;                   // 0..7: row within 8-row group
    const int sc = 8 * ((lane & 7) ^ sr);       // element col, pre-swizzled source
    const unsigned short* gA = A  + (size_t)(row0 + w * 8 + sr) * K + sc;
    const unsigned short* gB = Wt + (size_t)(col0 + w * 8 + sr) * K + sc;
    short* ldsA = As + (w * 8) * 64;            // wave-uniform dst base
    short* ldsB = Bs + (w * 8) * 64;

    f32x4 acc[4][4] = {};
    const int h = lane >> 4;                    // 0..3
    const int r15 = lane & 15;

    for (int k0 = 0; k0 < K; k0 += 64) {
        __syncthreads();
#pragma unroll
        for (int i = 0; i < 4; ++i) {
            async_copy16(gA + (size_t)i * 32 * K + k0, ldsA + i * 32 * 64);
            async_copy16(gB + (size_t)i * 32 * K + k0, ldsB + i * 32 * 64);
        }
        __syncthreads();
#pragma unroll
        for (int ks = 0; ks < 2; ++ks) {
            bf16x8 af[4], bfr[4];
#pragma unroll
            for (int i = 0; i < 4; ++i) {
                int ra = wr * 64 + i * 16 + r15;
                int offa = ra * 128 + ((ks * 64 + h * 16) ^ ((ra & 7) << 4));
                af[i] = *(const bf16x8*)((const char*)As + offa);
                int rb = wc * 64 + i * 16 + r15;
                int offb = rb * 128 + ((ks * 64 + h * 16) ^ ((rb & 7) << 4));
                bfr[i] = *(const bf16x8*)((const char*)Bs + offb);
            }
#pragma unroll
            for (int i = 0; i < 4; ++i)
#pragma unroll
                for (int j = 0; j < 4; ++j)
                    acc[i][j] = __builtin_amdgcn_mfma_f32_16x16x32_bf16(
                        af[i], bfr[j], acc[i][j], 0, 0, 0);
        }
    }

#pragma unroll
    for (int i = 0; i < 4; ++i) {
#pragma unroll
        for (int j = 0; j < 4; ++j) {
            int c = col0 + wc * 64 + j * 16 + r15;
            float bv = bias[c];
#pragma unroll
            for (int q = 0; q < 4; ++q) {
                int rr = row0 + wr * 64 + i * 16 + h * 4 + q;
                float v = acc[i][j][q] + bv;
                if (MODE == 2) v = gelu_f(v);
                if (MODE == 1) v += res[(size_t)rr * N + c];
                if (MODE == 1) ((float*)Cout)[(size_t)rr * N + c] = v;
                else ((unsigned short*)Cout)[(size_t)rr * N + c] = f2b(v);
            }
        }
    }
}

// ---------------- MFMA flash attention, 32x32 swapped-QK^T, in-register softmax --------
// grid = (B*H, T/128), block = 256 (4 waves). qy = 15 - blockIdx.y (LPT: longest first).
// Wave w owns q rows [q0 + 32w, q0 + 32w + 32). Per lane: q = q0 + 32w + (lane&31) FIXED.
// S^T = mfma(K, Q): lane holds 16 raw S values of ITS q row per 32-kv subtile.
// Softmax in exp2 domain: p = exp2(fma(s, SC, -m*SC)), SC = 0.125*log2(e); defer-max
// (THR=44 raw ~ 8 in log2 domain) skips sf/rescale on most subtiles. Pack via HW cvt_pk.
// O^T = mfma(V^T, P^T): accumulator col = q (lane-fixed) -> m/l/rescale pure per-lane.
__global__ __launch_bounds__(256) void attn_mfma(
    const unsigned short* __restrict__ qkv, unsigned short* __restrict__ y) {
    const int bh = blockIdx.x;
    const int b = bh >> 4, hh = bh & 15;
    const int qy = (int)gridDim.y - 1 - blockIdx.y;
    const int q0 = qy * 128;
    const int tid = threadIdx.x;
    const int lane = tid & 63, w = tid >> 6;
    const int hi = lane >> 5, q31 = lane & 31;

    const float SC  = 0.1803368801111244f;  // 0.125 * log2(e)
    const float THR = 44.0f;                // ~8 in log2 domain after scaling

    // LDS: K[64 kv][64 d] (8KB) + Vt[64 d][64 kv] (8KB); Os[128][68] f32 aliases both
    __shared__ __align__(16) char smem[128 * 68 * 4];
    short* Ks = (short*)smem;
    short* Vt = (short*)(smem + 8192);
    float (*Os)[68] = (float (*)[68])smem;

    const size_t base = (size_t)b * TDIM * (3 * CDIM);
    const unsigned short* qb = qkv + base + hh * DH;
    const unsigned short* kb = qkv + base + CDIM + hh * DH;
    const unsigned short* vb = qkv + base + 2 * CDIM + hh * DH;

    const int gq = q0 + w * 32 + q31;       // this lane's q row (global, within T)
    const int qmin_w = q0 + w * 32;
    const int qmax_w = qmin_w + 31;

    // Q B-frags: qf[ks] elem j = Q[gq][16*ks + 8*hi + j]
    bf16x8 qf[4];
#pragma unroll
    for (int ks = 0; ks < 4; ++ks)
        qf[ks] = *(const bf16x8*)(qb + (size_t)gq * (3 * CDIM) + ks * 16 + hi * 8);

    // staging geometry
    const int sr = lane >> 3;
    const int scK = 8 * ((lane & 7) ^ sr);  // pre-swizzled source col (elems)
    const int rV = tid >> 3;                // 0..31 kv row (+32)
    const int dblk = (tid & 7) * 8;

    f32x16 oacc[2] = {};                    // O^T: oacc[j2][r] = O[q][d=32*j2+(r&3)+8*(r>>2)+4*hi]
    float m = -1e30f, l = 0.f;

    const int NT = 2 * qy + 2;
    for (int kt = 0; kt < NT; ++kt) {
        const int kv0 = kt * 64;
        __syncthreads();
        // --- stage K tile (rows w*16..w*16+15) ---
#pragma unroll
        for (int i = 0; i < 2; ++i) {
            int rowbase = w * 16 + i * 8;
            async_copy16(kb + (size_t)(kv0 + rowbase + sr) * (3 * CDIM) + scK,
                         Ks + rowbase * 64);
        }
        // --- stage V transposed: Vt[d][kv], swizzle ((d^(d>>3))&7)<<4 ---
#pragma unroll
        for (int rd = 0; rd < 2; ++rd) {
            int r = rV + rd * 32;
            bf16x8 vv = *(const bf16x8*)(vb + (size_t)(kv0 + r) * (3 * CDIM) + dblk);
#pragma unroll
            for (int j = 0; j < 8; ++j) {
                int d = dblk + j;
                int off = d * 128 + ((2 * r) ^ (((d ^ (d >> 3)) & 7) << 4));
                *(short*)((char*)Vt + off) = vv[j];
            }
        }
        __syncthreads();

#pragma unroll
        for (int sub = 0; sub < 2; ++sub) {
            const int kvs = kv0 + sub * 32;
            if (kvs > qmax_w) break;        // wave-uniform

            // --- S^T subtile: rows kv (reg-mapped), col q (lane) ---
            f32x16 sacc = {};
            __builtin_amdgcn_s_setprio(1);
#pragma unroll
            for (int ks = 0; ks < 4; ++ks) {
                int row = sub * 32 + q31;
                int off = row * 128 + ((32 * ks + 16 * hi) ^ ((row & 7) << 4));
                bf16x8 kf = *(const bf16x8*)((const char*)Ks + off);
                sacc = __builtin_amdgcn_mfma_f32_32x32x16_bf16(kf, qf[ks], sacc, 0, 0, 0);
            }
            __builtin_amdgcn_s_setprio(0);

            // --- causal mask in raw domain (p[r]: kv = kvs + (r&3)+8*(r>>2)+4*hi) ---
            float p[16];
            if (kvs + 31 > qmin_w) {
#pragma unroll
                for (int r = 0; r < 16; ++r) {
                    int kvg = kvs + (r & 3) + 8 * (r >> 2) + 4 * hi;
                    p[r] = (kvg > gq) ? -1e30f : sacc[r];
                }
            } else {
#pragma unroll
                for (int r = 0; r < 16; ++r) p[r] = sacc[r];
            }

            // --- row max (raw domain) ---
            float t8[8];
#pragma unroll
            for (int r = 0; r < 8; ++r) t8[r] = fmaxf(p[r], p[r + 8]);
#pragma unroll
            for (int r = 0; r < 4; ++r) t8[r] = fmaxf(t8[r], t8[r + 4]);
            float pm = fmaxf(fmaxf(t8[0], t8[1]), fmaxf(t8[2], t8[3]));
            pm = fmaxf(pm, __shfl_xor(pm, 32));

            // --- defer-max: only rescale when the max moved materially ---
            if (!__all(pm <= m + THR)) {
                float mnew = fmaxf(m, pm);
                float sf = exp2f((m - mnew) * SC);
                m = mnew;
                l *= sf;
                oacc[0] *= sf;
                oacc[1] *= sf;
            }
            float mc = m * SC;
#pragma unroll
            for (int r = 0; r < 16; ++r) p[r] = exp2f(fmaf(p[r], SC, -mc));
#pragma unroll
            for (int r = 0; r < 8; ++r) t8[r] = p[r] + p[r + 8];
#pragma unroll
            for (int r = 0; r < 4; ++r) t8[r] = t8[r] + t8[r + 4];
            float rsum = (t8[0] + t8[1]) + (t8[2] + t8[3]);
            rsum += __shfl_xor(rsum, 32);
            l += rsum;

            // --- pack P -> PV B-frags (HW cvt_pk + half-swap) ---
            bf16x8 pa[2];
#pragma unroll
            for (int k2 = 0; k2 < 2; ++k2) {
                unsigned int A0 = cvtpk(p[8 * k2 + 0], p[8 * k2 + 1]);
                unsigned int A1 = cvtpk(p[8 * k2 + 2], p[8 * k2 + 3]);
                unsigned int B0 = cvtpk(p[8 * k2 + 4], p[8 * k2 + 5]);
                unsigned int B1 = cvtpk(p[8 * k2 + 6], p[8 * k2 + 7]);
                unsigned int sA0 = __shfl_xor((int)A0, 32);
                unsigned int sA1 = __shfl_xor((int)A1, 32);
                unsigned int sB0 = __shfl_xor((int)B0, 32);
                unsigned int sB1 = __shfl_xor((int)B1, 32);
                union { int i[4]; bf16x8 h; } u;
                u.i[0] = hi ? (int)sB0 : (int)A0;
                u.i[1] = hi ? (int)sB1 : (int)A1;
                u.i[2] = hi ? (int)B0 : (int)sA0;
                u.i[3] = hi ? (int)B1 : (int)sA1;
                pa[k2] = u.h;
            }

            // --- O^T += V^T @ P^T ---
            __builtin_amdgcn_s_setprio(1);
#pragma unroll
            for (int j2 = 0; j2 < 2; ++j2) {
                int row = 32 * j2 + q31;    // d row
                int swz = ((row ^ (row >> 3)) & 7) << 4;
#pragma unroll
                for (int k2 = 0; k2 < 2; ++k2) {
                    int off = row * 128 + ((64 * sub + 32 * k2 + 16 * hi) ^ swz);
                    bf16x8 vf = *(const bf16x8*)((const char*)Vt + off);
                    oacc[j2] = __builtin_amdgcn_mfma_f32_32x32x16_bf16(vf, pa[k2], oacc[j2], 0, 0, 0);
                }
            }
            __builtin_amdgcn_s_setprio(0);
        }
    }

    // --- epilogue: transpose O^T through LDS, coalesced bf16 store ---
    __syncthreads();                         // all K/V reads done; Os aliases them
    float invl = 1.0f / l;
#pragma unroll
    for (int j2 = 0; j2 < 2; ++j2)
#pragma unroll
        for (int g = 0; g < 4; ++g) {
            float4 v4 = make_float4(oacc[j2][4 * g + 0] * invl, oacc[j2][4 * g + 1] * invl,
                                    oacc[j2][4 * g + 2] * invl, oacc[j2][4 * g + 3] * invl);
            *(float4*)&Os[w * 32 + q31][32 * j2 + 8 * g + 4 * hi] = v4;
        }
    __syncthreads();
#pragma unroll
    for (int it = 0; it < 8; ++it) {
        int row = w * 32 + it * 4 + (lane >> 4);
        int col = (lane & 15) * 4;
        float4 v = *(const float4*)&Os[row][col];
        ushort4 o;
        o.x = f2b(v.x); o.y = f2b(v.y); o.z = f2b(v.z); o.w = f2b(v.w);
        *(ushort4*)(y + (size_t)(b * TDIM + q0 + row) * CDIM + hh * DH + col) = o;
    }
}

// ---------------- launch ----------------
extern "C" void kernel_launch(void* const* d_in, const int* in_sizes, int n_in,
                              void* d_out, int out_size, void* d_ws, size_t ws_size,
                              hipStream_t stream) {
    const float* x      = (const float*)d_in[0];
    const float* ln1_w  = (const float*)d_in[1];
    const float* ln1_b  = (const float*)d_in[2];
    const float* W_attn = (const float*)d_in[3];
    const float* b_attn = (const float*)d_in[4];
    const float* W_o    = (const float*)d_in[5];
    const float* b_o    = (const float*)d_in[6];
    const float* ln2_w  = (const float*)d_in[7];
    const float* ln2_b  = (const float*)d_in[8];
    const float* W_fc   = (const float*)d_in[9];
    const float* b_fc   = (const float*)d_in[10];
    const float* W_proj = (const float*)d_in[11];
    const float* b_proj = (const float*)d_in[12];
    float* out = (float*)d_out;

    char* ws = (char*)d_ws;
    const size_t MB = 1024 * 1024;
    unsigned short* h_bf    = (unsigned short*)(ws);             // 8 MB  [4096,1024]
    unsigned short* big     = (unsigned short*)(ws + 8 * MB);    // 32 MB qkv / fcact
    unsigned short* Wt_attn = (unsigned short*)(ws + 40 * MB);   // 6 MB  [3072,1024]
    unsigned short* Wt_o    = (unsigned short*)(ws + 46 * MB);   // 2 MB  [1024,1024]
    unsigned short* Wt_fc   = (unsigned short*)(ws + 48 * MB);   // 8 MB  [4096,1024]
    unsigned short* Wt_proj = (unsigned short*)(ws + 56 * MB);   // 8 MB  [1024,4096]
    float* x1 = out;

    // 0. weight transpose + cast (W[K][N] -> Wt[N][K] bf16)
    hipLaunchKernelGGL(transpose_cast, dim3(96, 32),  dim3(256), 0, stream, W_attn, Wt_attn, CDIM, 3 * CDIM);
    hipLaunchKernelGGL(transpose_cast, dim3(32, 32),  dim3(256), 0, stream, W_o,    Wt_o,    CDIM, CDIM);
    hipLaunchKernelGGL(transpose_cast, dim3(128, 32), dim3(256), 0, stream, W_fc,   Wt_fc,   CDIM, 4 * CDIM);
    hipLaunchKernelGGL(transpose_cast, dim3(32, 128), dim3(256), 0, stream, W_proj, Wt_proj, 4 * CDIM, CDIM);

    // 1. h = LN1(x)  (bf16)
    hipLaunchKernelGGL(ln_kernel, dim3(MDIM), dim3(256), 0, stream, x, ln1_w, ln1_b, h_bf);
    // 2. qkv = h @ W_attn + b_attn  -> bf16 [4096, 3072]
    hipLaunchKernelGGL((gemm_bf16<0>), dim3(3 * CDIM / 128, MDIM / 128), dim3(256), 0,
                       stream, h_bf, Wt_attn, b_attn, nullptr, big, MDIM, 3 * CDIM, CDIM);
    // 3. y = attention(qkv) -> h_bf (bf16)
    hipLaunchKernelGGL(attn_mfma, dim3(BDIM * HEADS, TDIM / 128), dim3(256), 0, stream,
                       big, h_bf);
    // 4. x1 = x + y @ W_o + b_o  (f32)
    hipLaunchKernelGGL((gemm_bf16<1>), dim3(CDIM / 128, MDIM / 128), dim3(256), 0,
                       stream, h_bf, Wt_o, b_o, x, x1, MDIM, CDIM, CDIM);
    // 5. h = LN2(x1) (bf16)
    hipLaunchKernelGGL(ln_kernel, dim3(MDIM), dim3(256), 0, stream, x1, ln2_w, ln2_b, h_bf);
    // 6. fcact = gelu(h @ W_fc + b_fc) -> bf16 [4096, 4096]
    hipLaunchKernelGGL((gemm_bf16<2>), dim3(4 * CDIM / 128, MDIM / 128), dim3(256), 0,
                       stream, h_bf, Wt_fc, b_fc, nullptr, big, MDIM, 4 * CDIM, CDIM);
    // 7. out = x1 + fcact @ W_proj + b_proj (f32)
    hipLaunchKernelGGL((gemm_bf16<1>), dim3(CDIM / 128, MDIM / 128), dim3(256), 0,
                       stream, big, Wt_proj, b_proj, x1, out, MDIM, CDIM, 4 * CDIM);
}